// Round 8
// baseline (238.756 us; speedup 1.0000x reference)
//
#include <hip/hip_runtime.h>
#include <math.h>

// Problem constants
#define BB 2
#define HH 64
#define WW 64
#define DM 192
#define DI 384
#define NS 16
#define DTR 12
#define LL 4096
#define ROWS (BB*LL)   // 8192
#define NCHUNK 64
#define LCHUNK 64      // NCHUNK*LCHUNK == LL
#define NCOMB 448      // padded combined-weight rows (416 real)
#define SROW 36        // LDS row stride (floats) for scan staging: conflict-free

typedef __attribute__((ext_vector_type(8))) short bf16x8;
typedef __attribute__((ext_vector_type(4))) float f32x4;

__device__ __forceinline__ float silu_f(float v) {
    return v / (1.0f + __expf(-v));
}

// fp32 -> bf16 (RNE) bit trick
__device__ __forceinline__ unsigned short f2bf(float f) {
    union { float f; unsigned int u; } c; c.f = f;
    unsigned int u = c.u;
    u += 0x7fffu + ((u >> 16) & 1u);
    return (unsigned short)(u >> 16);
}

__device__ __forceinline__ bf16x8 f2bf8(float4 a, float4 b) {
    bf16x8 r;
    r[0] = (short)f2bf(a.x); r[1] = (short)f2bf(a.y);
    r[2] = (short)f2bf(a.z); r[3] = (short)f2bf(a.w);
    r[4] = (short)f2bf(b.x); r[5] = (short)f2bf(b.y);
    r[6] = (short)f2bf(b.z); r[7] = (short)f2bf(b.w);
    return r;
}

// Cast the three static weights in one launch.
__global__ __launch_bounds__(256) void cast_weights(
    const float* __restrict__ w_in, const float* __restrict__ w_con,
    const float* __restrict__ w_out,
    unsigned short* __restrict__ w_in_bf, unsigned short* __restrict__ w_con_bf,
    unsigned short* __restrict__ w_out_bf)
{
    int i = blockIdx.x * 256 + threadIdx.x;   // float4 index, < 73728
    if (i >= 73728) return;
    const float4* src; ushort4* dst; int off;
    if (i < 36864)      { src = (const float4*)w_in;  dst = (ushort4*)w_in_bf;  off = i; }
    else if (i < 55296) { src = (const float4*)w_con; dst = (ushort4*)w_con_bf; off = i - 36864; }
    else                { src = (const float4*)w_out; dst = (ushort4*)w_out_bf; off = i - 55296; }
    float4 v = src[off];
    ushort4 o;
    o.x = f2bf(v.x); o.y = f2bf(v.y); o.z = f2bf(v.z); o.w = f2bf(v.w);
    dst[off] = o;
}

// ---------------------------------------------------------------------------
// Build combined weight Wc[448][384] in bf16.
// ---------------------------------------------------------------------------
__global__ __launch_bounds__(256) void make_wcomb(
    const float* __restrict__ x_proj_w,   // (44,384)
    const float* __restrict__ dt_w,       // (384,12)
    unsigned short* __restrict__ wc)
{
    int idx = blockIdx.x * 256 + threadIdx.x;   // < 448*384
    if (idx >= NCOMB * DI) return;
    int row = idx / DI, k = idx - row * DI;
    float v = 0.f;
    if (row < 384) {
        const float* dw = dt_w + row * DTR;
        #pragma unroll
        for (int r = 0; r < DTR; ++r) v += dw[r] * x_proj_w[r * DI + k];
    } else if (row < 416) {
        v = x_proj_w[(12 + (row - 384)) * DI + k];
    }
    wc[idx] = f2bf(v);
}

// ---------------------------------------------------------------------------
// Shared epilogue semantics:
// mode 0: N=768 split -> out0[row*384+col] raw (col<384), out1 = silu
// mode 1: plain out0[row*N+col]
// mode 2: col<384 -> out0 = softplus(v+bias[col]);
//         col in [384,400): B_n -> out1[row*32 + (n&7)*4 + (n>>3)]
//         col in [400,416): C_n -> out1[row*32 + (n&7)*4 + 2 + (n>>3)]
// ---------------------------------------------------------------------------
__device__ __forceinline__ void gemm_epilogue(
    int mode, int row, int col, int N, float v,
    const float* __restrict__ bias,
    float* __restrict__ out0, float* __restrict__ out1)
{
    if (mode == 0) {
        if (col < 384) out0[(size_t)row * 384 + col] = v;
        else           out1[(size_t)row * 384 + (col - 384)] = silu_f(v);
    } else if (mode == 1) {
        out0[(size_t)row * N + col] = v;
    } else {
        if (col < 384) {
            float a = v + bias[col];
            out0[(size_t)row * 384 + col] = (a > 20.f) ? a : log1pf(__expf(a));
        } else if (col < 416) {
            int idx = col - 384;
            int pos = (idx < 16) ? ((idx & 7) * 4 + (idx >> 3))
                                 : (((idx - 16) & 7) * 4 + 2 + ((idx - 16) >> 3));
            out1[(size_t)row * 32 + pos] = v;
        }
    }
}

// ---------------------------------------------------------------------------
// bf16 MFMA GEMM, 64x64 tile, BK=32, 256 threads. A is bf16.
// ---------------------------------------------------------------------------
__global__ __launch_bounds__(256) void gemm_bf16(
    const unsigned short* __restrict__ A, const unsigned short* __restrict__ W,
    const float* __restrict__ bias,
    float* __restrict__ out0, float* __restrict__ out1,
    int M, int N, int K, int mode)
{
    __shared__ __align__(16) unsigned short sA[64 * 40];
    __shared__ __align__(16) unsigned short sB[64 * 40];
    const int bm = blockIdx.x * 64;
    const int bn = blockIdx.y * 64;
    const int tid  = threadIdx.x;
    const int wave = tid >> 6;
    const int lane = tid & 63;
    const int quad = lane >> 4;
    const int l16  = lane & 15;
    const int lrow = tid >> 2;
    const int lkof = (tid & 3) * 8;

    f32x4 acc[4];
    #pragma unroll
    for (int t = 0; t < 4; ++t) acc[t] = (f32x4)(0.f);

    const int arow = (wave * 16 + l16) * 40 + quad * 8;

    for (int k0 = 0; k0 < K; k0 += 32) {
        *(bf16x8*)&sA[lrow * 40 + lkof] =
            *(const bf16x8*)&A[(size_t)(bm + lrow) * K + k0 + lkof];
        *(bf16x8*)&sB[lrow * 40 + lkof] =
            *(const bf16x8*)&W[(size_t)(bn + lrow) * K + k0 + lkof];
        __syncthreads();
        bf16x8 a = *(bf16x8*)&sA[arow];
        #pragma unroll
        for (int t = 0; t < 4; ++t) {
            bf16x8 b = *(bf16x8*)&sB[(t * 16 + l16) * 40 + quad * 8];
            acc[t] = __builtin_amdgcn_mfma_f32_16x16x32_bf16(a, b, acc[t], 0, 0, 0);
        }
        __syncthreads();
    }

    #pragma unroll
    for (int t = 0; t < 4; ++t) {
        int col = bn + t * 16 + l16;
        #pragma unroll
        for (int r = 0; r < 4; ++r) {
            int row = bm + wave * 16 + quad * 4 + r;
            gemm_epilogue(mode, row, col, N, acc[t][r], bias, out0, out1);
        }
    }
}

// ---------------------------------------------------------------------------
// Same GEMM but A is fp32 (cast to bf16 during staging — removes the
// standalone cast kernels and their HBM round trip).
// ---------------------------------------------------------------------------
__global__ __launch_bounds__(256) void gemm_bf16_f32a(
    const float* __restrict__ A, const unsigned short* __restrict__ W,
    const float* __restrict__ bias,
    float* __restrict__ out0, float* __restrict__ out1,
    int M, int N, int K, int mode)
{
    __shared__ __align__(16) unsigned short sA[64 * 40];
    __shared__ __align__(16) unsigned short sB[64 * 40];
    const int bm = blockIdx.x * 64;
    const int bn = blockIdx.y * 64;
    const int tid  = threadIdx.x;
    const int wave = tid >> 6;
    const int lane = tid & 63;
    const int quad = lane >> 4;
    const int l16  = lane & 15;
    const int lrow = tid >> 2;
    const int lkof = (tid & 3) * 8;

    f32x4 acc[4];
    #pragma unroll
    for (int t = 0; t < 4; ++t) acc[t] = (f32x4)(0.f);

    const int arow = (wave * 16 + l16) * 40 + quad * 8;

    for (int k0 = 0; k0 < K; k0 += 32) {
        const float* ap = &A[(size_t)(bm + lrow) * K + k0 + lkof];
        float4 a0 = *(const float4*)ap;
        float4 a1 = *(const float4*)(ap + 4);
        *(bf16x8*)&sA[lrow * 40 + lkof] = f2bf8(a0, a1);
        *(bf16x8*)&sB[lrow * 40 + lkof] =
            *(const bf16x8*)&W[(size_t)(bn + lrow) * K + k0 + lkof];
        __syncthreads();
        bf16x8 a = *(bf16x8*)&sA[arow];
        #pragma unroll
        for (int t = 0; t < 4; ++t) {
            bf16x8 b = *(bf16x8*)&sB[(t * 16 + l16) * 40 + quad * 8];
            acc[t] = __builtin_amdgcn_mfma_f32_16x16x32_bf16(a, b, acc[t], 0, 0, 0);
        }
        __syncthreads();
    }

    #pragma unroll
    for (int t = 0; t < 4; ++t) {
        int col = bn + t * 16 + l16;
        #pragma unroll
        for (int r = 0; r < 4; ++r) {
            int row = bm + wave * 16 + quad * 4 + r;
            gemm_epilogue(mode, row, col, N, acc[t][r], bias, out0, out1);
        }
    }
}

// ---------------------------------------------------------------------------
// Fused depthwise 3x3 convs + bias + silu; writes xs (fp32) and
// s = silu(conv_x)+silu(conv_c) as bf16, SCATTERED to scan order.
// ---------------------------------------------------------------------------
__global__ __launch_bounds__(256) void dwconv2_scatter(
    const float* __restrict__ xin, const float* __restrict__ cin,
    const float* __restrict__ wx, const float* __restrict__ bx,
    const float* __restrict__ wc, const float* __restrict__ bc,
    const int* __restrict__ rev_scan_path,
    float* __restrict__ xs_buf, unsigned short* __restrict__ s_bf)
{
    const int tile = blockIdx.x;
    const int c0   = blockIdx.y * 64;
    const int b    = blockIdx.z;
    const int h0 = (tile >> 3) * 8, w0 = (tile & 7) * 8;
    __shared__ float smx[10 * 10 * 64];
    __shared__ float smc[10 * 10 * 64];
    __shared__ int   jtile[64];

    for (int idx = threadIdx.x; idx < 6400; idx += 256) {
        int pix = idx >> 6, ch = idx & 63;
        int py = pix / 10, px = pix - py * 10;
        int gh = h0 + py - 1, gw = w0 + px - 1;
        float vx = 0.f, vc = 0.f;
        if (gh >= 0 && gh < 64 && gw >= 0 && gw < 64) {
            size_t g = ((size_t)(b * LL + gh * 64 + gw)) * DI + c0 + ch;
            vx = xin[g]; vc = cin[g];
        }
        smx[idx] = vx; smc[idx] = vc;
    }
    if (threadIdx.x < 64) {
        int l = (h0 + (threadIdx.x >> 3)) * 64 + (w0 + (threadIdx.x & 7));
        jtile[threadIdx.x] = rev_scan_path[l];
    }
    __syncthreads();

    const int ch = threadIdx.x & 63;
    const int pq = threadIdx.x >> 6;
    float wrx[9], wrc[9];
    #pragma unroll
    for (int k = 0; k < 9; ++k) {
        wrx[k] = wx[(c0 + ch) * 9 + k];
        wrc[k] = wc[(c0 + ch) * 9 + k];
    }
    const float bvx = bx[c0 + ch];
    const float bvc = bc[c0 + ch];

    #pragma unroll
    for (int i = 0; i < 16; ++i) {
        int p  = pq * 16 + i;
        int ph = p >> 3, pw = p & 7;
        float ax = bvx, ac = bvc;
        #pragma unroll
        for (int ki = 0; ki < 3; ++ki)
            #pragma unroll
            for (int kj = 0; kj < 3; ++kj) {
                int si = ((ph + ki) * 10 + (pw + kj)) * 64 + ch;
                ax += wrx[ki * 3 + kj] * smx[si];
                ac += wrc[ki * 3 + kj] * smc[si];
            }
        float xv = silu_f(ax);
        float sv = xv + silu_f(ac);
        size_t o = ((size_t)(b * LL + jtile[p])) * DI + c0 + ch;
        xs_buf[o] = xv;
        s_bf[o]   = f2bf(sv);
    }
}

// ---------------------------------------------------------------------------
// Scan staging helper: load the chunk's delta/xs/btct tiles into LDS with
// coalesced float4 loads. Row stride SROW=36 floats -> conflict-free writes.
// ---------------------------------------------------------------------------
__device__ __forceinline__ void stage_chunk(
    const float* __restrict__ delta, const float* __restrict__ xs,
    const float* __restrict__ btct, int b, int g, int j0, int t,
    float* sD, float* sU, float* sBC)
{
    const int row0 = t >> 3;        // 0..31
    const int c4   = t & 7;         // 0..7 (float4 col)
    #pragma unroll
    for (int it = 0; it < 2; ++it) {
        int row = row0 + it * 32;
        size_t gr = ((size_t)(b * LL + j0 + row));
        *(float4*)&sD[row * SROW + c4 * 4]  = *(const float4*)&delta[gr * DI + g * 32 + c4 * 4];
        *(float4*)&sU[row * SROW + c4 * 4]  = *(const float4*)&xs[gr * DI + g * 32 + c4 * 4];
        *(float4*)&sBC[row * SROW + c4 * 4] = *(const float4*)&btct[gr * 32 + c4 * 4];
    }
}

// ---------------------------------------------------------------------------
// Pass A: per-chunk composite. 8 lanes/channel, 2 states/lane.
// grid (NCHUNK, DI/32, BB). Composite layout TRANSPOSED: float2 index
// ((b*DI+d)*8+p)*NCHUNK + c  -> pass B reads contiguous per sequence.
// P computed as exp(Av * sum(delta)) — one exp at the end.
// ---------------------------------------------------------------------------
__global__ __launch_bounds__(256) void scan_chunkA(
    const float* __restrict__ xs, const float* __restrict__ delta,
    const float* __restrict__ btct, const float* __restrict__ A_logs,
    float* __restrict__ chunkA, float* __restrict__ chunkB)
{
    __shared__ __align__(16) float sD[LCHUNK * SROW];
    __shared__ __align__(16) float sU[LCHUNK * SROW];
    __shared__ __align__(16) float sBC[LCHUNK * SROW];
    const int c = blockIdx.x;
    const int g = blockIdx.y;
    const int b = blockIdx.z;
    const int t = threadIdx.x;
    const int grp = t >> 3, p = t & 7;
    const int d = g * 32 + grp;
    const float Av0 = -__expf(A_logs[d * NS + p]);
    const float Av1 = -__expf(A_logs[d * NS + p + 8]);
    const int j0 = c * LCHUNK;

    stage_chunk(delta, xs, btct, b, g, j0, t, sD, sU, sBC);
    __syncthreads();

    float h0 = 0.f, h1 = 0.f, Sdelta = 0.f;
    for (int j = 0; j < LCHUNK; j += 4) {
        #pragma unroll
        for (int q = 0; q < 4; ++q) {
            int jj = j + q;
            float dv = sD[jj * SROW + grp];
            float uv = sU[jj * SROW + grp];
            float2 bv = *(const float2*)&sBC[jj * SROW + p * 4];
            float e0 = __expf(dv * Av0);
            float e1 = __expf(dv * Av1);
            float du = dv * uv;
            h0 = e0 * h0 + bv.x * du;
            h1 = e1 * h1 + bv.y * du;
            Sdelta += dv;
        }
    }
    size_t idx = (((size_t)b * DI + d) * 8 + p) * NCHUNK + c;   // float2 index
    ((float2*)chunkA)[idx] = make_float2(__expf(Sdelta * Av0), __expf(Sdelta * Av1));
    ((float2*)chunkB)[idx] = make_float2(h0, h1);
}

// ---------------------------------------------------------------------------
// Pass B: serial combine — each thread owns one (b,d,p) sequence, reading
// its own CONTIGUOUS 64 float2s (512 B). 48 blocks x 256 threads.
// ---------------------------------------------------------------------------
__global__ __launch_bounds__(256) void scan_combine(
    const float* __restrict__ chunkA, const float* __restrict__ chunkB,
    float* __restrict__ hstart)
{
    const int gid = blockIdx.x * 256 + threadIdx.x;   // < BB*DI*8
    const float2* A2 = (const float2*)chunkA + (size_t)gid * NCHUNK;
    const float2* B2 = (const float2*)chunkB + (size_t)gid * NCHUNK;
    float2*       H2 = (float2*)hstart       + (size_t)gid * NCHUNK;
    float h0 = 0.f, h1 = 0.f;
    for (int c = 0; c < NCHUNK; ++c) {
        float2 a = A2[c], bv = B2[c];
        H2[c] = make_float2(h0, h1);
        h0 = a.x * h0 + bv.x;
        h1 = a.y * h1 + bv.y;
    }
}

// ---------------------------------------------------------------------------
// Pass C: local scan seeded with hstart, emit y. LDS-staged like pass A.
// ---------------------------------------------------------------------------
__global__ __launch_bounds__(256) void scan_chunkC(
    const float* __restrict__ xs, const float* __restrict__ delta,
    const float* __restrict__ btct,
    const float* __restrict__ A_logs, const float* __restrict__ Ds,
    const float* __restrict__ hstart,
    float* __restrict__ yt)
{
    __shared__ __align__(16) float sD[LCHUNK * SROW];
    __shared__ __align__(16) float sU[LCHUNK * SROW];
    __shared__ __align__(16) float sBC[LCHUNK * SROW];
    const int c = blockIdx.x;
    const int g = blockIdx.y;
    const int b = blockIdx.z;
    const int t = threadIdx.x;
    const int grp = t >> 3, p = t & 7;
    const int d = g * 32 + grp;
    const float Av0 = -__expf(A_logs[d * NS + p]);
    const float Av1 = -__expf(A_logs[d * NS + p + 8]);
    const float Dv = Ds[d];
    const int j0 = c * LCHUNK;

    stage_chunk(delta, xs, btct, b, g, j0, t, sD, sU, sBC);

    float2 h = ((const float2*)hstart)[(((size_t)b * DI + d) * 8 + p) * NCHUNK + c];
    float h0 = h.x, h1 = h.y;
    float* yl = yt + ((size_t)b * LL + j0) * DI + d;
    __syncthreads();

    for (int j = 0; j < LCHUNK; j += 4) {
        #pragma unroll
        for (int q = 0; q < 4; ++q) {
            int jj = j + q;
            float dv = sD[jj * SROW + grp];
            float uv = sU[jj * SROW + grp];
            float4 bc = *(const float4*)&sBC[jj * SROW + p * 4];
            float e0 = __expf(dv * Av0);
            float e1 = __expf(dv * Av1);
            float du = dv * uv;
            h0 = e0 * h0 + bc.x * du;
            h1 = e1 * h1 + bc.y * du;
            float acc = h0 * bc.z + h1 * bc.w;
            acc += __shfl_xor(acc, 4, 8);
            acc += __shfl_xor(acc, 2, 8);
            acc += __shfl_xor(acc, 1, 8);
            if (p == 0) yl[(size_t)jj * DI] = acc + uv * Dv;
        }
    }
}

// ---------------------------------------------------------------------------
// LayerNorm over d (384) + affine + z-mul; unpermute folded into write.
// ---------------------------------------------------------------------------
__global__ __launch_bounds__(128) void ln_mul(
    const float* __restrict__ yt, const float* __restrict__ z,
    const int* __restrict__ scan_path,
    const float* __restrict__ ln_w, const float* __restrict__ ln_b,
    unsigned short* __restrict__ yn)
{
    const int j = blockIdx.x;
    const int b = blockIdx.y;
    const int l = scan_path[j];
    const int t = threadIdx.x;
    const float* row = yt + ((size_t)(b * LL + j)) * DI;
    float v0 = row[t], v1 = row[t + 128], v2 = row[t + 256];
    float s  = v0 + v1 + v2;
    float s2 = v0*v0 + v1*v1 + v2*v2;
    #pragma unroll
    for (int off = 32; off > 0; off >>= 1) {
        s  += __shfl_down(s, off);
        s2 += __shfl_down(s2, off);
    }
    __shared__ float red[4];
    if ((t & 63) == 0) { red[(t >> 6) * 2] = s; red[(t >> 6) * 2 + 1] = s2; }
    __syncthreads();
    float S  = red[0] + red[2];
    float S2 = red[1] + red[3];
    float mu  = S * (1.0f / DI);
    float var = S2 * (1.0f / DI) - mu * mu;
    float inv = rsqrtf(var + 1e-5f);

    const float* zr = z + ((size_t)(b * LL + l)) * DI;
    unsigned short* o = yn + ((size_t)(b * LL + l)) * DI;
    o[t]       = f2bf(((v0 - mu) * inv * ln_w[t]       + ln_b[t])       * zr[t]);
    o[t + 128] = f2bf(((v1 - mu) * inv * ln_w[t + 128] + ln_b[t + 128]) * zr[t + 128]);
    o[t + 256] = f2bf(((v2 - mu) * inv * ln_w[t + 256] + ln_b[t + 256]) * zr[t + 256]);
}

// ---------------------------------------------------------------------------
extern "C" void kernel_launch(void* const* d_in, const int* in_sizes, int n_in,
                              void* d_out, int out_size, void* d_ws, size_t ws_size,
                              hipStream_t stream) {
    const float* x          = (const float*)d_in[0];
    const float* cond       = (const float*)d_in[1];
    const float* W_in       = (const float*)d_in[2];
    const float* W_con      = (const float*)d_in[3];
    const float* conv_w     = (const float*)d_in[4];
    const float* conv_b     = (const float*)d_in[5];
    const float* con_conv_w = (const float*)d_in[6];
    const float* con_conv_b = (const float*)d_in[7];
    const float* x_proj_w   = (const float*)d_in[8];
    const float* dt_proj_w  = (const float*)d_in[9];
    const float* dt_proj_b  = (const float*)d_in[10];
    const float* A_logs     = (const float*)d_in[11];
    const float* Ds         = (const float*)d_in[12];
    const float* ln_w       = (const float*)d_in[13];
    const float* ln_b       = (const float*)d_in[14];
    const float* W_out      = (const float*)d_in[15];
    const int*   scan_path  = (const int*)d_in[16];
    const int*   rev_path   = (const int*)d_in[17];

    float* ws = (float*)d_ws;
    const size_t S  = (size_t)BB * LL * DI;            // 3,145,728 floats
    const size_t SC = (size_t)NCHUNK * BB * DI * NS;   // 786,432 floats
    float* xa_pre  = ws + 0 * S;                       // reused later as yt
    float* z_silu  = ws + 1 * S;
    float* c_pre   = ws + 2 * S;                       // first half reused as yn_bf
    float* xs_buf  = ws + 3 * S;
    float* dl_buf  = ws + 4 * S;
    float* btct    = ws + 5 * S;                       // BB*LL*32 floats, packed
    float* chunkA  = btct + (size_t)BB * LL * 32;
    float* chunkB  = chunkA + SC;
    float* hstart  = chunkB + SC;
    float* bfpool  = hstart + SC;                      // bf16 staging area

    unsigned short* s_bf     = (unsigned short*)bfpool;            // ROWS*DI
    unsigned short* w_in_bf  = s_bf + (size_t)ROWS * DI;           // 768*192
    unsigned short* w_con_bf = w_in_bf + 768 * DM;                 // 384*192
    unsigned short* w_out_bf = w_con_bf + 384 * DM;                // 192*384
    unsigned short* wcomb_bf = w_out_bf + 192 * DI;                // 448*384
    unsigned short* yn_bf    = (unsigned short*)c_pre;             // ROWS*DI
    float* yt = xa_pre;

    // 0) weight casts + combined weight (no activation casts — folded into GEMMs)
    cast_weights<<<(73728 + 255) / 256, 256, 0, stream>>>(
        W_in, W_con, W_out, w_in_bf, w_con_bf, w_out_bf);
    make_wcomb<<<(NCOMB * DI + 255) / 256, 256, 0, stream>>>(x_proj_w, dt_proj_w, wcomb_bf);

    // 1) xz = x @ W_in.T  -> xa_pre (raw), z_silu (silu)   [fp32 A]
    gemm_bf16_f32a<<<dim3(ROWS / 64, 768 / 64), 256, 0, stream>>>(
        x, w_in_bf, nullptr, xa_pre, z_silu, ROWS, 768, DM, 0);
    // 2) c = cond @ W_con.T -> c_pre                        [fp32 A]
    gemm_bf16_f32a<<<dim3(ROWS / 64, 384 / 64), 256, 0, stream>>>(
        cond, w_con_bf, nullptr, c_pre, nullptr, ROWS, 384, DM, 1);
    // 3) fused depthwise convs + silu + scatter to scan order (s in bf16)
    dwconv2_scatter<<<dim3(64, 6, BB), 256, 0, stream>>>(
        xa_pre, c_pre, conv_w, conv_b, con_conv_w, con_conv_b,
        rev_path, xs_buf, s_bf);
    // 4) combined GEMM: delta (softplus) + packed btct
    gemm_bf16<<<dim3(ROWS / 64, NCOMB / 64), 256, 0, stream>>>(
        s_bf, wcomb_bf, dt_proj_b, dl_buf, btct, ROWS, NCOMB, DI, 2);
    // 5) chunked parallel scan (3 passes, LDS-staged)
    scan_chunkA<<<dim3(NCHUNK, DI / 32, BB), 256, 0, stream>>>(
        xs_buf, dl_buf, btct, A_logs, chunkA, chunkB);
    scan_combine<<<(BB * DI * 8) / 256, 256, 0, stream>>>(chunkA, chunkB, hstart);
    scan_chunkC<<<dim3(NCHUNK, DI / 32, BB), 256, 0, stream>>>(
        xs_buf, dl_buf, btct, A_logs, Ds, hstart, yt);
    // 6) LN + z-mul (unpermute folded in), yn in bf16
    ln_mul<<<dim3(LL, BB), 128, 0, stream>>>(yt, z_silu, scan_path, ln_w, ln_b, yn_bf);
    // 7) out = yn @ W_out.T
    gemm_bf16<<<dim3(ROWS / 64, 192 / 64), 256, 0, stream>>>(
        yn_bf, w_out_bf, nullptr, (float*)d_out, nullptr, ROWS, DM, DI, 1);
}

// Round 9
// 238.121 us; speedup vs baseline: 1.0027x; 1.0027x over previous
//
#include <hip/hip_runtime.h>
#include <math.h>

// Problem constants
#define BB 2
#define HH 64
#define WW 64
#define DM 192
#define DI 384
#define NS 16
#define DTR 12
#define LL 4096
#define ROWS (BB*LL)   // 8192
#define NCHUNK 64
#define LCHUNK 64      // NCHUNK*LCHUNK == LL
#define NCOMB 448      // padded combined-weight rows (416 real)

typedef __attribute__((ext_vector_type(8))) short bf16x8;
typedef __attribute__((ext_vector_type(4))) float f32x4;

__device__ __forceinline__ float silu_f(float v) {
    return v / (1.0f + __expf(-v));
}

// fp32 -> bf16 (RNE) bit trick
__device__ __forceinline__ unsigned short f2bf(float f) {
    union { float f; unsigned int u; } c; c.f = f;
    unsigned int u = c.u;
    u += 0x7fffu + ((u >> 16) & 1u);
    return (unsigned short)(u >> 16);
}

__device__ __forceinline__ bf16x8 f2bf8(float4 a, float4 b) {
    bf16x8 r;
    r[0] = (short)f2bf(a.x); r[1] = (short)f2bf(a.y);
    r[2] = (short)f2bf(a.z); r[3] = (short)f2bf(a.w);
    r[4] = (short)f2bf(b.x); r[5] = (short)f2bf(b.y);
    r[6] = (short)f2bf(b.z); r[7] = (short)f2bf(b.w);
    return r;
}

// ---------------------------------------------------------------------------
// One prep kernel: cast W_in/W_con/W_out to bf16 AND build combined weight
// Wc[448][384] (rows 0..383 = dt_w @ x_proj_w[:12], 384..415 = B/C rows).
// Work items: [0, 73728) float4 casts; [73728, 73728+172032) wcomb scalars.
// ---------------------------------------------------------------------------
__global__ __launch_bounds__(256) void prep_weights(
    const float* __restrict__ w_in, const float* __restrict__ w_con,
    const float* __restrict__ w_out,
    const float* __restrict__ x_proj_w, const float* __restrict__ dt_w,
    unsigned short* __restrict__ w_in_bf, unsigned short* __restrict__ w_con_bf,
    unsigned short* __restrict__ w_out_bf, unsigned short* __restrict__ wc)
{
    int idx = blockIdx.x * 256 + threadIdx.x;
    if (idx < 73728) {
        const float4* src; ushort4* dst; int off;
        if (idx < 36864)      { src = (const float4*)w_in;  dst = (ushort4*)w_in_bf;  off = idx; }
        else if (idx < 55296) { src = (const float4*)w_con; dst = (ushort4*)w_con_bf; off = idx - 36864; }
        else                  { src = (const float4*)w_out; dst = (ushort4*)w_out_bf; off = idx - 55296; }
        float4 v = src[off];
        ushort4 o;
        o.x = f2bf(v.x); o.y = f2bf(v.y); o.z = f2bf(v.z); o.w = f2bf(v.w);
        dst[off] = o;
    } else {
        int e = idx - 73728;                      // < 448*384
        if (e >= NCOMB * DI) return;
        int row = e / DI, k = e - row * DI;
        float v = 0.f;
        if (row < 384) {
            const float* dw = dt_w + row * DTR;
            #pragma unroll
            for (int r = 0; r < DTR; ++r) v += dw[r] * x_proj_w[r * DI + k];
        } else if (row < 416) {
            v = x_proj_w[(12 + (row - 384)) * DI + k];
        }
        wc[e] = f2bf(v);
    }
}

// ---------------------------------------------------------------------------
// Shared epilogue semantics:
// mode 0: N=768 split -> out0[row*384+col] raw (col<384), out1 = silu
// mode 1: plain out0[row*N+col]
// mode 2: col<384 -> out0 = softplus(v+bias[col]);
//         col in [384,400): B_n -> out1[row*32 + (n&7)*4 + (n>>3)]
//         col in [400,416): C_n -> out1[row*32 + (n&7)*4 + 2 + (n>>3)]
// ---------------------------------------------------------------------------
__device__ __forceinline__ void gemm_epilogue(
    int mode, int row, int col, int N, float v,
    const float* __restrict__ bias,
    float* __restrict__ out0, float* __restrict__ out1)
{
    if (mode == 0) {
        if (col < 384) out0[(size_t)row * 384 + col] = v;
        else           out1[(size_t)row * 384 + (col - 384)] = silu_f(v);
    } else if (mode == 1) {
        out0[(size_t)row * N + col] = v;
    } else {
        if (col < 384) {
            float a = v + bias[col];
            out0[(size_t)row * 384 + col] = (a > 20.f) ? a : log1pf(__expf(a));
        } else if (col < 416) {
            int idx = col - 384;
            int pos = (idx < 16) ? ((idx & 7) * 4 + (idx >> 3))
                                 : (((idx - 16) & 7) * 4 + 2 + ((idx - 16) >> 3));
            out1[(size_t)row * 32 + pos] = v;
        }
    }
}

// ---------------------------------------------------------------------------
// bf16 MFMA GEMM, 64x64 tile, BK=32, 256 threads. A is bf16.
// ---------------------------------------------------------------------------
__global__ __launch_bounds__(256) void gemm_bf16(
    const unsigned short* __restrict__ A, const unsigned short* __restrict__ W,
    const float* __restrict__ bias,
    float* __restrict__ out0, float* __restrict__ out1,
    int M, int N, int K, int mode)
{
    __shared__ __align__(16) unsigned short sA[64 * 40];
    __shared__ __align__(16) unsigned short sB[64 * 40];
    const int bm = blockIdx.x * 64;
    const int bn = blockIdx.y * 64;
    const int tid  = threadIdx.x;
    const int wave = tid >> 6;
    const int lane = tid & 63;
    const int quad = lane >> 4;
    const int l16  = lane & 15;
    const int lrow = tid >> 2;
    const int lkof = (tid & 3) * 8;

    f32x4 acc[4];
    #pragma unroll
    for (int t = 0; t < 4; ++t) acc[t] = (f32x4)(0.f);

    const int arow = (wave * 16 + l16) * 40 + quad * 8;

    for (int k0 = 0; k0 < K; k0 += 32) {
        *(bf16x8*)&sA[lrow * 40 + lkof] =
            *(const bf16x8*)&A[(size_t)(bm + lrow) * K + k0 + lkof];
        *(bf16x8*)&sB[lrow * 40 + lkof] =
            *(const bf16x8*)&W[(size_t)(bn + lrow) * K + k0 + lkof];
        __syncthreads();
        bf16x8 a = *(bf16x8*)&sA[arow];
        #pragma unroll
        for (int t = 0; t < 4; ++t) {
            bf16x8 b = *(bf16x8*)&sB[(t * 16 + l16) * 40 + quad * 8];
            acc[t] = __builtin_amdgcn_mfma_f32_16x16x32_bf16(a, b, acc[t], 0, 0, 0);
        }
        __syncthreads();
    }

    #pragma unroll
    for (int t = 0; t < 4; ++t) {
        int col = bn + t * 16 + l16;
        #pragma unroll
        for (int r = 0; r < 4; ++r) {
            int row = bm + wave * 16 + quad * 4 + r;
            gemm_epilogue(mode, row, col, N, acc[t][r], bias, out0, out1);
        }
    }
}

// ---------------------------------------------------------------------------
// Dual GEMM: z=0 -> xz = x @ W_in.T (mode 0, N=768); z=1 -> c = cond @
// W_con.T (mode 1, N=384). fp32 A cast to bf16 during staging. Merging the
// two independent GEMMs removes a serial stream boundary.
// ---------------------------------------------------------------------------
__global__ __launch_bounds__(256) void gemm_dual(
    const float* __restrict__ x, const float* __restrict__ cond,
    const unsigned short* __restrict__ w_in_bf,
    const unsigned short* __restrict__ w_con_bf,
    float* __restrict__ xa_pre, float* __restrict__ z_silu,
    float* __restrict__ c_pre)
{
    const int zz = blockIdx.z;
    if (zz == 1 && blockIdx.y >= 6) return;
    const float* A = zz ? cond : x;
    const unsigned short* W = zz ? w_con_bf : w_in_bf;
    float* out0 = zz ? c_pre : xa_pre;
    float* out1 = z_silu;
    const int mode = zz ? 1 : 0;
    const int N = zz ? 384 : 768;

    __shared__ __align__(16) unsigned short sA[64 * 40];
    __shared__ __align__(16) unsigned short sB[64 * 40];
    const int bm = blockIdx.x * 64;
    const int bn = blockIdx.y * 64;
    const int tid  = threadIdx.x;
    const int wave = tid >> 6;
    const int lane = tid & 63;
    const int quad = lane >> 4;
    const int l16  = lane & 15;
    const int lrow = tid >> 2;
    const int lkof = (tid & 3) * 8;

    f32x4 acc[4];
    #pragma unroll
    for (int t = 0; t < 4; ++t) acc[t] = (f32x4)(0.f);

    const int arow = (wave * 16 + l16) * 40 + quad * 8;

    for (int k0 = 0; k0 < DM; k0 += 32) {
        const float* ap = &A[(size_t)(bm + lrow) * DM + k0 + lkof];
        float4 a0 = *(const float4*)ap;
        float4 a1 = *(const float4*)(ap + 4);
        *(bf16x8*)&sA[lrow * 40 + lkof] = f2bf8(a0, a1);
        *(bf16x8*)&sB[lrow * 40 + lkof] =
            *(const bf16x8*)&W[(size_t)(bn + lrow) * DM + k0 + lkof];
        __syncthreads();
        bf16x8 a = *(bf16x8*)&sA[arow];
        #pragma unroll
        for (int t = 0; t < 4; ++t) {
            bf16x8 b = *(bf16x8*)&sB[(t * 16 + l16) * 40 + quad * 8];
            acc[t] = __builtin_amdgcn_mfma_f32_16x16x32_bf16(a, b, acc[t], 0, 0, 0);
        }
        __syncthreads();
    }

    #pragma unroll
    for (int t = 0; t < 4; ++t) {
        int col = bn + t * 16 + l16;
        #pragma unroll
        for (int r = 0; r < 4; ++r) {
            int row = bm + wave * 16 + quad * 4 + r;
            gemm_epilogue(mode, row, col, N, acc[t][r], nullptr, out0, out1);
        }
    }
}

// ---------------------------------------------------------------------------
// Fused depthwise 3x3 convs + bias + silu; writes xs (fp32) and
// s = silu(conv_x)+silu(conv_c) as bf16, SCATTERED to scan order.
// ---------------------------------------------------------------------------
__global__ __launch_bounds__(256) void dwconv2_scatter(
    const float* __restrict__ xin, const float* __restrict__ cin,
    const float* __restrict__ wx, const float* __restrict__ bx,
    const float* __restrict__ wc, const float* __restrict__ bc,
    const int* __restrict__ rev_scan_path,
    float* __restrict__ xs_buf, unsigned short* __restrict__ s_bf)
{
    const int tile = blockIdx.x;
    const int c0   = blockIdx.y * 64;
    const int b    = blockIdx.z;
    const int h0 = (tile >> 3) * 8, w0 = (tile & 7) * 8;
    __shared__ float smx[10 * 10 * 64];
    __shared__ float smc[10 * 10 * 64];
    __shared__ int   jtile[64];

    for (int idx = threadIdx.x; idx < 6400; idx += 256) {
        int pix = idx >> 6, ch = idx & 63;
        int py = pix / 10, px = pix - py * 10;
        int gh = h0 + py - 1, gw = w0 + px - 1;
        float vx = 0.f, vc = 0.f;
        if (gh >= 0 && gh < 64 && gw >= 0 && gw < 64) {
            size_t g = ((size_t)(b * LL + gh * 64 + gw)) * DI + c0 + ch;
            vx = xin[g]; vc = cin[g];
        }
        smx[idx] = vx; smc[idx] = vc;
    }
    if (threadIdx.x < 64) {
        int l = (h0 + (threadIdx.x >> 3)) * 64 + (w0 + (threadIdx.x & 7));
        jtile[threadIdx.x] = rev_scan_path[l];
    }
    __syncthreads();

    const int ch = threadIdx.x & 63;
    const int pq = threadIdx.x >> 6;
    float wrx[9], wrc[9];
    #pragma unroll
    for (int k = 0; k < 9; ++k) {
        wrx[k] = wx[(c0 + ch) * 9 + k];
        wrc[k] = wc[(c0 + ch) * 9 + k];
    }
    const float bvx = bx[c0 + ch];
    const float bvc = bc[c0 + ch];

    #pragma unroll
    for (int i = 0; i < 16; ++i) {
        int p  = pq * 16 + i;
        int ph = p >> 3, pw = p & 7;
        float ax = bvx, ac = bvc;
        #pragma unroll
        for (int ki = 0; ki < 3; ++ki)
            #pragma unroll
            for (int kj = 0; kj < 3; ++kj) {
                int si = ((ph + ki) * 10 + (pw + kj)) * 64 + ch;
                ax += wrx[ki * 3 + kj] * smx[si];
                ac += wrc[ki * 3 + kj] * smc[si];
            }
        float xv = silu_f(ax);
        float sv = xv + silu_f(ac);
        size_t o = ((size_t)(b * LL + jtile[p])) * DI + c0 + ch;
        xs_buf[o] = xv;
        s_bf[o]   = f2bf(sv);
    }
}

// ---------------------------------------------------------------------------
// Pass A: per-chunk composite, register-prefetch (r7 structure). 8 lanes per
// channel, 2 states per lane. grid (NCHUNK, DI/32, BB). Composite layout
// TRANSPOSED: float2 index ((b*DI+d)*8+p)*NCHUNK + c. Chunk decay computed
// as exp(Av * sum(delta)) — one exp at the end.
// ---------------------------------------------------------------------------
__global__ __launch_bounds__(256) void scan_chunkA(
    const float* __restrict__ xs, const float* __restrict__ delta,
    const float* __restrict__ btct, const float* __restrict__ A_logs,
    float* __restrict__ chunkA, float* __restrict__ chunkB)
{
    const int c = blockIdx.x;
    const int g = blockIdx.y;
    const int b = blockIdx.z;
    const int t = threadIdx.x;
    const int grp = t >> 3, p = t & 7;
    const int d = g * 32 + grp;
    const float Av0 = -__expf(A_logs[d * NS + p]);
    const float Av1 = -__expf(A_logs[d * NS + p + 8]);
    const int j0 = c * LCHUNK;

    const float*  dl = delta + ((size_t)b * LL + j0) * DI + d;
    const float*  ul = xs    + ((size_t)b * LL + j0) * DI + d;
    const float2* bl = (const float2*)btct + ((size_t)b * LL + j0) * 16 + p * 2;

    float h0 = 0.f, h1 = 0.f, Sd = 0.f;
    float dv[4], uv[4]; float2 bv[4];
    #pragma unroll
    for (int q = 0; q < 4; ++q) {
        dv[q] = dl[(size_t)q * DI]; uv[q] = ul[(size_t)q * DI]; bv[q] = bl[(size_t)q * 16];
    }
    for (int j = 0; j < LCHUNK; j += 4) {
        float nd[4], nu[4]; float2 nb[4];
        if (j + 4 < LCHUNK) {
            #pragma unroll
            for (int q = 0; q < 4; ++q) {
                int jj = j + 4 + q;
                nd[q] = dl[(size_t)jj * DI]; nu[q] = ul[(size_t)jj * DI]; nb[q] = bl[(size_t)jj * 16];
            }
        }
        #pragma unroll
        for (int q = 0; q < 4; ++q) {
            float e0 = __expf(dv[q] * Av0);
            float e1 = __expf(dv[q] * Av1);
            float du = dv[q] * uv[q];
            h0 = e0 * h0 + bv[q].x * du;
            h1 = e1 * h1 + bv[q].y * du;
            Sd += dv[q];
        }
        #pragma unroll
        for (int q = 0; q < 4; ++q) { dv[q]=nd[q]; uv[q]=nu[q]; bv[q]=nb[q]; }
    }
    size_t idx = (((size_t)b * DI + d) * 8 + p) * NCHUNK + c;   // float2 index
    ((float2*)chunkA)[idx] = make_float2(__expf(Sd * Av0), __expf(Sd * Av1));
    ((float2*)chunkB)[idx] = make_float2(h0, h1);
}

// ---------------------------------------------------------------------------
// Pass B: serial combine — each thread owns one (b,d,p) sequence, reading
// its own CONTIGUOUS 64 float2s (512 B). 24 blocks x 256 threads.
// ---------------------------------------------------------------------------
__global__ __launch_bounds__(256) void scan_combine(
    const float* __restrict__ chunkA, const float* __restrict__ chunkB,
    float* __restrict__ hstart)
{
    const int gid = blockIdx.x * 256 + threadIdx.x;   // < BB*DI*8
    const float2* A2 = (const float2*)chunkA + (size_t)gid * NCHUNK;
    const float2* B2 = (const float2*)chunkB + (size_t)gid * NCHUNK;
    float2*       H2 = (float2*)hstart       + (size_t)gid * NCHUNK;
    float h0 = 0.f, h1 = 0.f;
    for (int c = 0; c < NCHUNK; ++c) {
        float2 a = A2[c], bv = B2[c];
        H2[c] = make_float2(h0, h1);
        h0 = a.x * h0 + bv.x;
        h1 = a.y * h1 + bv.y;
    }
}

// ---------------------------------------------------------------------------
// Pass C: local scan seeded with hstart, register-prefetch (r7 structure).
// btct packed as [j][p][B_p, B_{p+8}, C_p, C_{p+8}] -> one dwordx4 per step.
// ---------------------------------------------------------------------------
__global__ __launch_bounds__(256) void scan_chunkC(
    const float* __restrict__ xs, const float* __restrict__ delta,
    const float* __restrict__ btct,
    const float* __restrict__ A_logs, const float* __restrict__ Ds,
    const float* __restrict__ hstart,
    float* __restrict__ yt)
{
    const int c = blockIdx.x;
    const int g = blockIdx.y;
    const int b = blockIdx.z;
    const int t = threadIdx.x;
    const int grp = t >> 3, p = t & 7;
    const int d = g * 32 + grp;
    const float Av0 = -__expf(A_logs[d * NS + p]);
    const float Av1 = -__expf(A_logs[d * NS + p + 8]);
    const float Dv = Ds[d];
    const int j0 = c * LCHUNK;

    const float*  dl  = delta + ((size_t)b * LL + j0) * DI + d;
    const float*  ul  = xs    + ((size_t)b * LL + j0) * DI + d;
    const float4* bcl = (const float4*)btct + ((size_t)b * LL + j0) * 8 + p;
    float* yl = yt + ((size_t)b * LL + j0) * DI + d;

    float2 h = ((const float2*)hstart)[(((size_t)b * DI + d) * 8 + p) * NCHUNK + c];
    float h0 = h.x, h1 = h.y;

    float dv[4], uv[4]; float4 bc[4];
    #pragma unroll
    for (int q = 0; q < 4; ++q) {
        dv[q] = dl[(size_t)q * DI]; uv[q] = ul[(size_t)q * DI]; bc[q] = bcl[(size_t)q * 8];
    }
    for (int j = 0; j < LCHUNK; j += 4) {
        float nd[4], nu[4]; float4 nbc[4];
        if (j + 4 < LCHUNK) {
            #pragma unroll
            for (int q = 0; q < 4; ++q) {
                int jj = j + 4 + q;
                nd[q] = dl[(size_t)jj * DI]; nu[q] = ul[(size_t)jj * DI]; nbc[q] = bcl[(size_t)jj * 8];
            }
        }
        #pragma unroll
        for (int q = 0; q < 4; ++q) {
            float e0 = __expf(dv[q] * Av0);
            float e1 = __expf(dv[q] * Av1);
            float du = dv[q] * uv[q];
            h0 = e0 * h0 + bc[q].x * du;
            h1 = e1 * h1 + bc[q].y * du;
            float acc = h0 * bc[q].z + h1 * bc[q].w;
            acc += __shfl_xor(acc, 4, 8);
            acc += __shfl_xor(acc, 2, 8);
            acc += __shfl_xor(acc, 1, 8);
            if (p == 0) yl[(size_t)(j + q) * DI] = acc + uv[q] * Dv;
        }
        #pragma unroll
        for (int q = 0; q < 4; ++q) { dv[q]=nd[q]; uv[q]=nu[q]; bc[q]=nbc[q]; }
    }
}

// ---------------------------------------------------------------------------
// Fused LayerNorm + z-mul + final GEMM (out = LN(yt)[unperm] * z @ W_out.T).
// Block = 32 output rows x 192 cols, 256 threads.
// Phase 1: gather yt rows (j = rev_path), LN + affine + z, write bf16 to sA.
// Phase 2: 32x192x384 MFMA GEMM from sA, W staged per-k into sB.
// Removes the yn HBM round trip entirely.
// ---------------------------------------------------------------------------
__global__ __launch_bounds__(256) void ln_gemm(
    const float* __restrict__ yt, const float* __restrict__ z,
    const int* __restrict__ rev_path,
    const float* __restrict__ ln_w, const float* __restrict__ ln_b,
    const unsigned short* __restrict__ w_out_bf,   // (192,384)
    float* __restrict__ out)
{
    __shared__ __align__(16) unsigned short sA[32 * 392];  // 392 = 384+8 pad
    __shared__ __align__(16) unsigned short sB[192 * 40];
    const int l0 = blockIdx.x * 32;
    const int tid  = threadIdx.x;
    const int wave = tid >> 6;
    const int lane = tid & 63;

    // Phase 1: LN rows (each wave handles 8 rows)
    for (int r = wave; r < 32; r += 4) {
        int gl = l0 + r;
        int b = gl >> 12;                 // LL = 4096
        int pos = gl & (LL - 1);
        int j = b * LL + rev_path[pos];
        const float* yrow = yt + (size_t)j * DI;
        float v[6];
        float s = 0.f, s2 = 0.f;
        #pragma unroll
        for (int i = 0; i < 6; ++i) {
            v[i] = yrow[lane + 64 * i];
            s += v[i]; s2 += v[i] * v[i];
        }
        #pragma unroll
        for (int off = 32; off > 0; off >>= 1) {
            s  += __shfl_xor(s, off);
            s2 += __shfl_xor(s2, off);
        }
        float mu  = s * (1.0f / DI);
        float var = s2 * (1.0f / DI) - mu * mu;
        float inv = rsqrtf(var + 1e-5f);
        const float* zrow = z + (size_t)gl * DI;
        #pragma unroll
        for (int i = 0; i < 6; ++i) {
            int cidx = lane + 64 * i;
            float val = ((v[i] - mu) * inv * ln_w[cidx] + ln_b[cidx]) * zrow[cidx];
            sA[r * 392 + cidx] = f2bf(val);
        }
    }
    __syncthreads();

    // Phase 2: GEMM 32x192, K=384
    const int quad = lane >> 4;
    const int l16  = lane & 15;
    const int wr  = wave >> 1;        // row half (0/1)
    const int wc2 = wave & 1;         // col half (0/1)
    const int r2  = tid >> 2;         // 0..63
    const int kof = (tid & 3) * 8;

    f32x4 acc[6];
    #pragma unroll
    for (int cI = 0; cI < 6; ++cI) acc[cI] = (f32x4)(0.f);

    for (int k0 = 0; k0 < DI; k0 += 32) {
        #pragma unroll
        for (int it = 0; it < 3; ++it) {
            int row = r2 + it * 64;   // 0..191
            *(bf16x8*)&sB[row * 40 + kof] =
                *(const bf16x8*)&w_out_bf[(size_t)row * DI + k0 + kof];
        }
        __syncthreads();
        bf16x8 a = *(bf16x8*)&sA[(wr * 16 + l16) * 392 + k0 + quad * 8];
        #pragma unroll
        for (int cI = 0; cI < 6; ++cI) {
            bf16x8 bb = *(bf16x8*)&sB[(wc2 * 96 + cI * 16 + l16) * 40 + quad * 8];
            acc[cI] = __builtin_amdgcn_mfma_f32_16x16x32_bf16(a, bb, acc[cI], 0, 0, 0);
        }
        __syncthreads();
    }

    #pragma unroll
    for (int cI = 0; cI < 6; ++cI) {
        int col = wc2 * 96 + cI * 16 + l16;
        #pragma unroll
        for (int r = 0; r < 4; ++r) {
            int row = l0 + wr * 16 + quad * 4 + r;
            out[(size_t)row * DM + col] = acc[cI][r];
        }
    }
}

// ---------------------------------------------------------------------------
extern "C" void kernel_launch(void* const* d_in, const int* in_sizes, int n_in,
                              void* d_out, int out_size, void* d_ws, size_t ws_size,
                              hipStream_t stream) {
    const float* x          = (const float*)d_in[0];
    const float* cond       = (const float*)d_in[1];
    const float* W_in       = (const float*)d_in[2];
    const float* W_con      = (const float*)d_in[3];
    const float* conv_w     = (const float*)d_in[4];
    const float* conv_b     = (const float*)d_in[5];
    const float* con_conv_w = (const float*)d_in[6];
    const float* con_conv_b = (const float*)d_in[7];
    const float* x_proj_w   = (const float*)d_in[8];
    const float* dt_proj_w  = (const float*)d_in[9];
    const float* dt_proj_b  = (const float*)d_in[10];
    const float* A_logs     = (const float*)d_in[11];
    const float* Ds         = (const float*)d_in[12];
    const float* ln_w       = (const float*)d_in[13];
    const float* ln_b       = (const float*)d_in[14];
    const float* W_out      = (const float*)d_in[15];
    const int*   scan_path  = (const int*)d_in[16];
    const int*   rev_path   = (const int*)d_in[17];
    (void)scan_path;

    float* ws = (float*)d_ws;
    const size_t S  = (size_t)BB * LL * DI;            // 3,145,728 floats
    const size_t SC = (size_t)NCHUNK * BB * DI * NS;   // 786,432 floats
    float* xa_pre  = ws + 0 * S;                       // reused later as yt
    float* z_silu  = ws + 1 * S;
    float* c_pre   = ws + 2 * S;
    float* xs_buf  = ws + 3 * S;
    float* dl_buf  = ws + 4 * S;
    float* btct    = ws + 5 * S;                       // BB*LL*32 floats, packed
    float* chunkA  = btct + (size_t)BB * LL * 32;
    float* chunkB  = chunkA + SC;
    float* hstart  = chunkB + SC;
    float* bfpool  = hstart + SC;                      // bf16 staging area

    unsigned short* s_bf     = (unsigned short*)bfpool;            // ROWS*DI
    unsigned short* w_in_bf  = s_bf + (size_t)ROWS * DI;           // 768*192
    unsigned short* w_con_bf = w_in_bf + 768 * DM;                 // 384*192
    unsigned short* w_out_bf = w_con_bf + 384 * DM;                // 192*384
    unsigned short* wcomb_bf = w_out_bf + 192 * DI;                // 448*384
    float* yt = xa_pre;

    // 0) weight prep (casts + combined weight), one launch
    prep_weights<<<(73728 + NCOMB * DI + 255) / 256, 256, 0, stream>>>(
        W_in, W_con, W_out, x_proj_w, dt_proj_w,
        w_in_bf, w_con_bf, w_out_bf, wcomb_bf);

    // 1+2) dual GEMM: xz = x @ W_in.T (split+silu) AND c = cond @ W_con.T
    gemm_dual<<<dim3(ROWS / 64, 12, 2), 256, 0, stream>>>(
        x, cond, w_in_bf, w_con_bf, xa_pre, z_silu, c_pre);
    // 3) fused depthwise convs + silu + scatter to scan order (s in bf16)
    dwconv2_scatter<<<dim3(64, 6, BB), 256, 0, stream>>>(
        xa_pre, c_pre, conv_w, conv_b, con_conv_w, con_conv_b,
        rev_path, xs_buf, s_bf);
    // 4) combined GEMM: delta (softplus) + packed btct
    gemm_bf16<<<dim3(ROWS / 64, NCOMB / 64), 256, 0, stream>>>(
        s_bf, wcomb_bf, dt_proj_b, dl_buf, btct, ROWS, NCOMB, DI, 2);
    // 5) chunked parallel scan (3 passes, register-prefetch)
    scan_chunkA<<<dim3(NCHUNK, DI / 32, BB), 256, 0, stream>>>(
        xs_buf, dl_buf, btct, A_logs, chunkA, chunkB);
    scan_combine<<<(BB * DI * 8) / 256, 256, 0, stream>>>(chunkA, chunkB, hstart);
    scan_chunkC<<<dim3(NCHUNK, DI / 32, BB), 256, 0, stream>>>(
        xs_buf, dl_buf, btct, A_logs, Ds, hstart, yt);
    // 6+7) fused LN + z-mul + out = yn @ W_out.T
    ln_gemm<<<ROWS / 32, 256, 0, stream>>>(
        yt, z_silu, rev_path, ln_w, ln_b, w_out_bf, (float*)d_out);
}

// Round 10
// 231.833 us; speedup vs baseline: 1.0299x; 1.0271x over previous
//
#include <hip/hip_runtime.h>
#include <math.h>

// Problem constants
#define BB 2
#define HH 64
#define WW 64
#define DM 192
#define DI 384
#define NS 16
#define DTR 12
#define LL 4096
#define ROWS (BB*LL)   // 8192
#define NCHUNK 64
#define LCHUNK 64      // NCHUNK*LCHUNK == LL
#define NCOMB 448      // padded combined-weight rows (416 real)

typedef __attribute__((ext_vector_type(8))) short bf16x8;
typedef __attribute__((ext_vector_type(4))) float f32x4;

__device__ __forceinline__ float silu_f(float v) {
    return v / (1.0f + __expf(-v));
}

// fp32 -> bf16 (RNE) bit trick
__device__ __forceinline__ unsigned short f2bf(float f) {
    union { float f; unsigned int u; } c; c.f = f;
    unsigned int u = c.u;
    u += 0x7fffu + ((u >> 16) & 1u);
    return (unsigned short)(u >> 16);
}
__device__ __forceinline__ float bf2f(unsigned short h) {
    union { unsigned int u; float f; } c; c.u = ((unsigned int)h) << 16;
    return c.f;
}

__device__ __forceinline__ bf16x8 f2bf8(float4 a, float4 b) {
    bf16x8 r;
    r[0] = (short)f2bf(a.x); r[1] = (short)f2bf(a.y);
    r[2] = (short)f2bf(a.z); r[3] = (short)f2bf(a.w);
    r[4] = (short)f2bf(b.x); r[5] = (short)f2bf(b.y);
    r[6] = (short)f2bf(b.z); r[7] = (short)f2bf(b.w);
    return r;
}

// ---------------------------------------------------------------------------
// One prep kernel: cast W_in/W_con/W_out to bf16 AND build combined weight
// Wc[448][384] (rows 0..383 = dt_w @ x_proj_w[:12], 384..415 = B/C rows).
// ---------------------------------------------------------------------------
__global__ __launch_bounds__(256) void prep_weights(
    const float* __restrict__ w_in, const float* __restrict__ w_con,
    const float* __restrict__ w_out,
    const float* __restrict__ x_proj_w, const float* __restrict__ dt_w,
    unsigned short* __restrict__ w_in_bf, unsigned short* __restrict__ w_con_bf,
    unsigned short* __restrict__ w_out_bf, unsigned short* __restrict__ wc)
{
    int idx = blockIdx.x * 256 + threadIdx.x;
    if (idx < 73728) {
        const float4* src; ushort4* dst; int off;
        if (idx < 36864)      { src = (const float4*)w_in;  dst = (ushort4*)w_in_bf;  off = idx; }
        else if (idx < 55296) { src = (const float4*)w_con; dst = (ushort4*)w_con_bf; off = idx - 36864; }
        else                  { src = (const float4*)w_out; dst = (ushort4*)w_out_bf; off = idx - 55296; }
        float4 v = src[off];
        ushort4 o;
        o.x = f2bf(v.x); o.y = f2bf(v.y); o.z = f2bf(v.z); o.w = f2bf(v.w);
        dst[off] = o;
    } else {
        int e = idx - 73728;                      // < 448*384
        if (e >= NCOMB * DI) return;
        int row = e / DI, k = e - row * DI;
        float v = 0.f;
        if (row < 384) {
            const float* dw = dt_w + row * DTR;
            #pragma unroll
            for (int r = 0; r < DTR; ++r) v += dw[r] * x_proj_w[r * DI + k];
        } else if (row < 416) {
            v = x_proj_w[(12 + (row - 384)) * DI + k];
        }
        wc[e] = f2bf(v);
    }
}

// ---------------------------------------------------------------------------
// Shared epilogue semantics:
// mode 0: N=768 split -> out0[row*384+col] raw (col<384),
//         col>=384 -> ((ushort*)out1)[row*384+col-384] = bf16(silu(v))
// mode 1: plain ((float*)out0)[row*N+col]
// mode 2: col<384 -> out0 = softplus(v+bias[col]);
//         col in [384,400): B_n -> ((float*)out1)[row*32 + (n&7)*4 + (n>>3)]
//         col in [400,416): C_n -> ((float*)out1)[row*32 + (n&7)*4 + 2 + (n>>3)]
// ---------------------------------------------------------------------------
__device__ __forceinline__ void gemm_epilogue(
    int mode, int row, int col, int N, float v,
    const float* __restrict__ bias,
    float* __restrict__ out0, void* __restrict__ out1)
{
    if (mode == 0) {
        if (col < 384) out0[(size_t)row * 384 + col] = v;
        else ((unsigned short*)out1)[(size_t)row * 384 + (col - 384)] = f2bf(silu_f(v));
    } else if (mode == 1) {
        out0[(size_t)row * N + col] = v;
    } else {
        if (col < 384) {
            float a = v + bias[col];
            out0[(size_t)row * 384 + col] = (a > 20.f) ? a : log1pf(__expf(a));
        } else if (col < 416) {
            int idx = col - 384;
            int pos = (idx < 16) ? ((idx & 7) * 4 + (idx >> 3))
                                 : (((idx - 16) & 7) * 4 + 2 + ((idx - 16) >> 3));
            ((float*)out1)[(size_t)row * 32 + pos] = v;
        }
    }
}

// ---------------------------------------------------------------------------
// bf16 MFMA GEMM, 64x64 tile, BK=32, 256 threads. A is bf16.
// ---------------------------------------------------------------------------
__global__ __launch_bounds__(256) void gemm_bf16(
    const unsigned short* __restrict__ A, const unsigned short* __restrict__ W,
    const float* __restrict__ bias,
    float* __restrict__ out0, void* __restrict__ out1,
    int M, int N, int K, int mode)
{
    __shared__ __align__(16) unsigned short sA[64 * 40];
    __shared__ __align__(16) unsigned short sB[64 * 40];
    const int bm = blockIdx.x * 64;
    const int bn = blockIdx.y * 64;
    const int tid  = threadIdx.x;
    const int wave = tid >> 6;
    const int lane = tid & 63;
    const int quad = lane >> 4;
    const int l16  = lane & 15;
    const int lrow = tid >> 2;
    const int lkof = (tid & 3) * 8;

    f32x4 acc[4];
    #pragma unroll
    for (int t = 0; t < 4; ++t) acc[t] = (f32x4)(0.f);

    const int arow = (wave * 16 + l16) * 40 + quad * 8;

    for (int k0 = 0; k0 < K; k0 += 32) {
        *(bf16x8*)&sA[lrow * 40 + lkof] =
            *(const bf16x8*)&A[(size_t)(bm + lrow) * K + k0 + lkof];
        *(bf16x8*)&sB[lrow * 40 + lkof] =
            *(const bf16x8*)&W[(size_t)(bn + lrow) * K + k0 + lkof];
        __syncthreads();
        bf16x8 a = *(bf16x8*)&sA[arow];
        #pragma unroll
        for (int t = 0; t < 4; ++t) {
            bf16x8 b = *(bf16x8*)&sB[(t * 16 + l16) * 40 + quad * 8];
            acc[t] = __builtin_amdgcn_mfma_f32_16x16x32_bf16(a, b, acc[t], 0, 0, 0);
        }
        __syncthreads();
    }

    #pragma unroll
    for (int t = 0; t < 4; ++t) {
        int col = bn + t * 16 + l16;
        #pragma unroll
        for (int r = 0; r < 4; ++r) {
            int row = bm + wave * 16 + quad * 4 + r;
            gemm_epilogue(mode, row, col, N, acc[t][r], bias, out0, out1);
        }
    }
}

// ---------------------------------------------------------------------------
// Dual GEMM: z=0 -> xz = x @ W_in.T (mode 0, N=768); z=1 -> c = cond @
// W_con.T (mode 1, N=384). fp32 A cast to bf16 during staging. Concurrent
// execution of the two independent GEMMs (graph nodes serialize otherwise).
// ---------------------------------------------------------------------------
__global__ __launch_bounds__(256) void gemm_dual(
    const float* __restrict__ x, const float* __restrict__ cond,
    const unsigned short* __restrict__ w_in_bf,
    const unsigned short* __restrict__ w_con_bf,
    float* __restrict__ xa_pre, unsigned short* __restrict__ z_bf,
    float* __restrict__ c_pre)
{
    const int zz = blockIdx.z;
    if (zz == 1 && blockIdx.y >= 6) return;
    const float* A = zz ? cond : x;
    const unsigned short* W = zz ? w_con_bf : w_in_bf;
    float* out0 = zz ? c_pre : xa_pre;
    const int mode = zz ? 1 : 0;
    const int N = zz ? 384 : 768;

    __shared__ __align__(16) unsigned short sA[64 * 40];
    __shared__ __align__(16) unsigned short sB[64 * 40];
    const int bm = blockIdx.x * 64;
    const int bn = blockIdx.y * 64;
    const int tid  = threadIdx.x;
    const int wave = tid >> 6;
    const int lane = tid & 63;
    const int quad = lane >> 4;
    const int l16  = lane & 15;
    const int lrow = tid >> 2;
    const int lkof = (tid & 3) * 8;

    f32x4 acc[4];
    #pragma unroll
    for (int t = 0; t < 4; ++t) acc[t] = (f32x4)(0.f);

    const int arow = (wave * 16 + l16) * 40 + quad * 8;

    for (int k0 = 0; k0 < DM; k0 += 32) {
        const float* ap = &A[(size_t)(bm + lrow) * DM + k0 + lkof];
        float4 a0 = *(const float4*)ap;
        float4 a1 = *(const float4*)(ap + 4);
        *(bf16x8*)&sA[lrow * 40 + lkof] = f2bf8(a0, a1);
        *(bf16x8*)&sB[lrow * 40 + lkof] =
            *(const bf16x8*)&W[(size_t)(bn + lrow) * DM + k0 + lkof];
        __syncthreads();
        bf16x8 a = *(bf16x8*)&sA[arow];
        #pragma unroll
        for (int t = 0; t < 4; ++t) {
            bf16x8 b = *(bf16x8*)&sB[(t * 16 + l16) * 40 + quad * 8];
            acc[t] = __builtin_amdgcn_mfma_f32_16x16x32_bf16(a, b, acc[t], 0, 0, 0);
        }
        __syncthreads();
    }

    #pragma unroll
    for (int t = 0; t < 4; ++t) {
        int col = bn + t * 16 + l16;
        #pragma unroll
        for (int r = 0; r < 4; ++r) {
            int row = bm + wave * 16 + quad * 4 + r;
            gemm_epilogue(mode, row, col, N, acc[t][r], nullptr, out0, (void*)z_bf);
        }
    }
}

// ---------------------------------------------------------------------------
// Fused depthwise 3x3 convs + bias + silu; writes xs (fp32) and
// s = silu(conv_x)+silu(conv_c) as bf16, SCATTERED to scan order.
// 32-channel groups: LDS 25.6 KB -> 6 blocks/CU; grid (64, 12, B).
// ---------------------------------------------------------------------------
__global__ __launch_bounds__(256) void dwconv2_scatter(
    const float* __restrict__ xin, const float* __restrict__ cin,
    const float* __restrict__ wx, const float* __restrict__ bx,
    const float* __restrict__ wc, const float* __restrict__ bc,
    const int* __restrict__ rev_scan_path,
    float* __restrict__ xs_buf, unsigned short* __restrict__ s_bf)
{
    const int tile = blockIdx.x;
    const int c0   = blockIdx.y * 32;
    const int b    = blockIdx.z;
    const int h0 = (tile >> 3) * 8, w0 = (tile & 7) * 8;
    __shared__ float smx[10 * 10 * 32];
    __shared__ float smc[10 * 10 * 32];
    __shared__ int   jtile[64];

    for (int idx = threadIdx.x; idx < 3200; idx += 256) {
        int pix = idx >> 5, ch = idx & 31;
        int py = pix / 10, px = pix - py * 10;
        int gh = h0 + py - 1, gw = w0 + px - 1;
        float vx = 0.f, vc = 0.f;
        if (gh >= 0 && gh < 64 && gw >= 0 && gw < 64) {
            size_t g = ((size_t)(b * LL + gh * 64 + gw)) * DI + c0 + ch;
            vx = xin[g]; vc = cin[g];
        }
        smx[idx] = vx; smc[idx] = vc;
    }
    if (threadIdx.x < 64) {
        int l = (h0 + (threadIdx.x >> 3)) * 64 + (w0 + (threadIdx.x & 7));
        jtile[threadIdx.x] = rev_scan_path[l];
    }
    __syncthreads();

    const int ch = threadIdx.x & 31;
    const int pq = threadIdx.x >> 5;   // 0..7
    float wrx[9], wrc[9];
    #pragma unroll
    for (int k = 0; k < 9; ++k) {
        wrx[k] = wx[(c0 + ch) * 9 + k];
        wrc[k] = wc[(c0 + ch) * 9 + k];
    }
    const float bvx = bx[c0 + ch];
    const float bvc = bc[c0 + ch];

    #pragma unroll
    for (int i = 0; i < 8; ++i) {
        int p  = pq * 8 + i;           // 0..63
        int ph = p >> 3, pw = p & 7;
        float ax = bvx, ac = bvc;
        #pragma unroll
        for (int ki = 0; ki < 3; ++ki)
            #pragma unroll
            for (int kj = 0; kj < 3; ++kj) {
                int si = ((ph + ki) * 10 + (pw + kj)) * 32 + ch;
                ax += wrx[ki * 3 + kj] * smx[si];
                ac += wrc[ki * 3 + kj] * smc[si];
            }
        float xv = silu_f(ax);
        float sv = xv + silu_f(ac);
        size_t o = ((size_t)(b * LL + jtile[p])) * DI + c0 + ch;
        xs_buf[o] = xv;
        s_bf[o]   = f2bf(sv);
    }
}

// ---------------------------------------------------------------------------
// Pass A: per-chunk composite, register-prefetch. 8 lanes/channel, 2 states
// per lane. grid (NCHUNK, DI/32, BB). Composite layout TRANSPOSED: float2
// index ((b*DI+d)*8+p)*NCHUNK + c. Chunk decay = exp(Av * sum(delta)).
// ---------------------------------------------------------------------------
__global__ __launch_bounds__(256) void scan_chunkA(
    const float* __restrict__ xs, const float* __restrict__ delta,
    const float* __restrict__ btct, const float* __restrict__ A_logs,
    float* __restrict__ chunkA, float* __restrict__ chunkB)
{
    const int c = blockIdx.x;
    const int g = blockIdx.y;
    const int b = blockIdx.z;
    const int t = threadIdx.x;
    const int grp = t >> 3, p = t & 7;
    const int d = g * 32 + grp;
    const float Av0 = -__expf(A_logs[d * NS + p]);
    const float Av1 = -__expf(A_logs[d * NS + p + 8]);
    const int j0 = c * LCHUNK;

    const float*  dl = delta + ((size_t)b * LL + j0) * DI + d;
    const float*  ul = xs    + ((size_t)b * LL + j0) * DI + d;
    const float2* bl = (const float2*)btct + ((size_t)b * LL + j0) * 16 + p * 2;

    float h0 = 0.f, h1 = 0.f, Sd = 0.f;
    float dv[4], uv[4]; float2 bv[4];
    #pragma unroll
    for (int q = 0; q < 4; ++q) {
        dv[q] = dl[(size_t)q * DI]; uv[q] = ul[(size_t)q * DI]; bv[q] = bl[(size_t)q * 16];
    }
    for (int j = 0; j < LCHUNK; j += 4) {
        float nd[4], nu[4]; float2 nb[4];
        if (j + 4 < LCHUNK) {
            #pragma unroll
            for (int q = 0; q < 4; ++q) {
                int jj = j + 4 + q;
                nd[q] = dl[(size_t)jj * DI]; nu[q] = ul[(size_t)jj * DI]; nb[q] = bl[(size_t)jj * 16];
            }
        }
        #pragma unroll
        for (int q = 0; q < 4; ++q) {
            float e0 = __expf(dv[q] * Av0);
            float e1 = __expf(dv[q] * Av1);
            float du = dv[q] * uv[q];
            h0 = e0 * h0 + bv[q].x * du;
            h1 = e1 * h1 + bv[q].y * du;
            Sd += dv[q];
        }
        #pragma unroll
        for (int q = 0; q < 4; ++q) { dv[q]=nd[q]; uv[q]=nu[q]; bv[q]=nb[q]; }
    }
    size_t idx = (((size_t)b * DI + d) * 8 + p) * NCHUNK + c;   // float2 index
    ((float2*)chunkA)[idx] = make_float2(__expf(Sd * Av0), __expf(Sd * Av1));
    ((float2*)chunkB)[idx] = make_float2(h0, h1);
}

// ---------------------------------------------------------------------------
// Pass B: serial combine — each thread owns one (b,d,p) sequence, contiguous.
// ---------------------------------------------------------------------------
__global__ __launch_bounds__(256) void scan_combine(
    const float* __restrict__ chunkA, const float* __restrict__ chunkB,
    float* __restrict__ hstart)
{
    const int gid = blockIdx.x * 256 + threadIdx.x;   // < BB*DI*8
    const float2* A2 = (const float2*)chunkA + (size_t)gid * NCHUNK;
    const float2* B2 = (const float2*)chunkB + (size_t)gid * NCHUNK;
    float2*       H2 = (float2*)hstart       + (size_t)gid * NCHUNK;
    float h0 = 0.f, h1 = 0.f;
    for (int c = 0; c < NCHUNK; ++c) {
        float2 a = A2[c], bv = B2[c];
        H2[c] = make_float2(h0, h1);
        h0 = a.x * h0 + bv.x;
        h1 = a.y * h1 + bv.y;
    }
}

// ---------------------------------------------------------------------------
// Pass C: local scan seeded with hstart, register-prefetch.
// ---------------------------------------------------------------------------
__global__ __launch_bounds__(256) void scan_chunkC(
    const float* __restrict__ xs, const float* __restrict__ delta,
    const float* __restrict__ btct,
    const float* __restrict__ A_logs, const float* __restrict__ Ds,
    const float* __restrict__ hstart,
    float* __restrict__ yt)
{
    const int c = blockIdx.x;
    const int g = blockIdx.y;
    const int b = blockIdx.z;
    const int t = threadIdx.x;
    const int grp = t >> 3, p = t & 7;
    const int d = g * 32 + grp;
    const float Av0 = -__expf(A_logs[d * NS + p]);
    const float Av1 = -__expf(A_logs[d * NS + p + 8]);
    const float Dv = Ds[d];
    const int j0 = c * LCHUNK;

    const float*  dl  = delta + ((size_t)b * LL + j0) * DI + d;
    const float*  ul  = xs    + ((size_t)b * LL + j0) * DI + d;
    const float4* bcl = (const float4*)btct + ((size_t)b * LL + j0) * 8 + p;
    float* yl = yt + ((size_t)b * LL + j0) * DI + d;

    float2 h = ((const float2*)hstart)[(((size_t)b * DI + d) * 8 + p) * NCHUNK + c];
    float h0 = h.x, h1 = h.y;

    float dv[4], uv[4]; float4 bc[4];
    #pragma unroll
    for (int q = 0; q < 4; ++q) {
        dv[q] = dl[(size_t)q * DI]; uv[q] = ul[(size_t)q * DI]; bc[q] = bcl[(size_t)q * 8];
    }
    for (int j = 0; j < LCHUNK; j += 4) {
        float nd[4], nu[4]; float4 nbc[4];
        if (j + 4 < LCHUNK) {
            #pragma unroll
            for (int q = 0; q < 4; ++q) {
                int jj = j + 4 + q;
                nd[q] = dl[(size_t)jj * DI]; nu[q] = ul[(size_t)jj * DI]; nbc[q] = bcl[(size_t)jj * 8];
            }
        }
        #pragma unroll
        for (int q = 0; q < 4; ++q) {
            float e0 = __expf(dv[q] * Av0);
            float e1 = __expf(dv[q] * Av1);
            float du = dv[q] * uv[q];
            h0 = e0 * h0 + bc[q].x * du;
            h1 = e1 * h1 + bc[q].y * du;
            float acc = h0 * bc[q].z + h1 * bc[q].w;
            acc += __shfl_xor(acc, 4, 8);
            acc += __shfl_xor(acc, 2, 8);
            acc += __shfl_xor(acc, 1, 8);
            if (p == 0) yl[(size_t)(j + q) * DI] = acc + uv[q] * Dv;
        }
        #pragma unroll
        for (int q = 0; q < 4; ++q) { dv[q]=nd[q]; uv[q]=nu[q]; bc[q]=nbc[q]; }
    }
}

// ---------------------------------------------------------------------------
// LayerNorm over d (384) + affine + z-mul (z in bf16); unpermute folded into
// write; yn out in bf16. 128 threads, 3 elems/thread.
// ---------------------------------------------------------------------------
__global__ __launch_bounds__(128) void ln_mul(
    const float* __restrict__ yt, const unsigned short* __restrict__ z,
    const int* __restrict__ scan_path,
    const float* __restrict__ ln_w, const float* __restrict__ ln_b,
    unsigned short* __restrict__ yn)
{
    const int j = blockIdx.x;
    const int b = blockIdx.y;
    const int l = scan_path[j];
    const int t = threadIdx.x;
    const float* row = yt + ((size_t)(b * LL + j)) * DI;
    float v0 = row[t], v1 = row[t + 128], v2 = row[t + 256];
    float s  = v0 + v1 + v2;
    float s2 = v0*v0 + v1*v1 + v2*v2;
    #pragma unroll
    for (int off = 32; off > 0; off >>= 1) {
        s  += __shfl_down(s, off);
        s2 += __shfl_down(s2, off);
    }
    __shared__ float red[4];
    if ((t & 63) == 0) { red[(t >> 6) * 2] = s; red[(t >> 6) * 2 + 1] = s2; }
    __syncthreads();
    float S  = red[0] + red[2];
    float S2 = red[1] + red[3];
    float mu  = S * (1.0f / DI);
    float var = S2 * (1.0f / DI) - mu * mu;
    float inv = rsqrtf(var + 1e-5f);

    const unsigned short* zr = z + ((size_t)(b * LL + l)) * DI;
    unsigned short* o = yn + ((size_t)(b * LL + l)) * DI;
    o[t]       = f2bf(((v0 - mu) * inv * ln_w[t]       + ln_b[t])       * bf2f(zr[t]));
    o[t + 128] = f2bf(((v1 - mu) * inv * ln_w[t + 128] + ln_b[t + 128]) * bf2f(zr[t + 128]));
    o[t + 256] = f2bf(((v2 - mu) * inv * ln_w[t + 256] + ln_b[t + 256]) * bf2f(zr[t + 256]));
}

// ---------------------------------------------------------------------------
extern "C" void kernel_launch(void* const* d_in, const int* in_sizes, int n_in,
                              void* d_out, int out_size, void* d_ws, size_t ws_size,
                              hipStream_t stream) {
    const float* x          = (const float*)d_in[0];
    const float* cond       = (const float*)d_in[1];
    const float* W_in       = (const float*)d_in[2];
    const float* W_con      = (const float*)d_in[3];
    const float* conv_w     = (const float*)d_in[4];
    const float* conv_b     = (const float*)d_in[5];
    const float* con_conv_w = (const float*)d_in[6];
    const float* con_conv_b = (const float*)d_in[7];
    const float* x_proj_w   = (const float*)d_in[8];
    const float* dt_proj_w  = (const float*)d_in[9];
    const float* dt_proj_b  = (const float*)d_in[10];
    const float* A_logs     = (const float*)d_in[11];
    const float* Ds         = (const float*)d_in[12];
    const float* ln_w       = (const float*)d_in[13];
    const float* ln_b       = (const float*)d_in[14];
    const float* W_out      = (const float*)d_in[15];
    const int*   scan_path  = (const int*)d_in[16];
    const int*   rev_path   = (const int*)d_in[17];

    float* ws = (float*)d_ws;
    const size_t S  = (size_t)BB * LL * DI;            // 3,145,728 floats
    const size_t SC = (size_t)NCHUNK * BB * DI * NS;   // 786,432 floats
    float* xa_pre  = ws + 0 * S;                       // reused later as yt
    float* zslab   = ws + 1 * S;                       // z_bf (ushort, half used)
    float* c_pre   = ws + 2 * S;                       // reused as yn_bf
    float* xs_buf  = ws + 3 * S;
    float* dl_buf  = ws + 4 * S;
    float* btct    = ws + 5 * S;                       // BB*LL*32 floats, packed
    float* chunkA  = btct + (size_t)BB * LL * 32;
    float* chunkB  = chunkA + SC;
    float* hstart  = chunkB + SC;
    float* bfpool  = hstart + SC;                      // bf16 staging area

    unsigned short* z_bf     = (unsigned short*)zslab;             // ROWS*DI
    unsigned short* s_bf     = (unsigned short*)bfpool;            // ROWS*DI
    unsigned short* w_in_bf  = s_bf + (size_t)ROWS * DI;           // 768*192
    unsigned short* w_con_bf = w_in_bf + 768 * DM;                 // 384*192
    unsigned short* w_out_bf = w_con_bf + 384 * DM;                // 192*384
    unsigned short* wcomb_bf = w_out_bf + 192 * DI;                // 448*384
    unsigned short* yn_bf    = (unsigned short*)c_pre;             // ROWS*DI
    float* yt = xa_pre;

    // 0) weight prep (casts + combined weight), one launch
    prep_weights<<<(73728 + NCOMB * DI + 255) / 256, 256, 0, stream>>>(
        W_in, W_con, W_out, x_proj_w, dt_proj_w,
        w_in_bf, w_con_bf, w_out_bf, wcomb_bf);

    // 1+2) dual GEMM: xz = x @ W_in.T (split, z->bf16 silu) AND c = cond @ W_con.T
    gemm_dual<<<dim3(ROWS / 64, 12, 2), 256, 0, stream>>>(
        x, cond, w_in_bf, w_con_bf, xa_pre, z_bf, c_pre);
    // 3) fused depthwise convs + silu + scatter to scan order (32-ch groups)
    dwconv2_scatter<<<dim3(64, 12, BB), 256, 0, stream>>>(
        xa_pre, c_pre, conv_w, conv_b, con_conv_w, con_conv_b,
        rev_path, xs_buf, s_bf);
    // 4) combined GEMM: delta (softplus) + packed btct
    gemm_bf16<<<dim3(ROWS / 64, NCOMB / 64), 256, 0, stream>>>(
        s_bf, wcomb_bf, dt_proj_b, dl_buf, (void*)btct, ROWS, NCOMB, DI, 2);
    // 5) chunked parallel scan (3 passes)
    scan_chunkA<<<dim3(NCHUNK, DI / 32, BB), 256, 0, stream>>>(
        xs_buf, dl_buf, btct, A_logs, chunkA, chunkB);
    scan_combine<<<(BB * DI * 8) / 256, 256, 0, stream>>>(chunkA, chunkB, hstart);
    scan_chunkC<<<dim3(NCHUNK, DI / 32, BB), 256, 0, stream>>>(
        xs_buf, dl_buf, btct, A_logs, Ds, hstart, yt);
    // 6) LN + z-mul (unpermute folded in), yn in bf16
    ln_mul<<<dim3(LL, BB), 128, 0, stream>>>(yt, z_bf, scan_path, ln_w, ln_b, yn_bf);
    // 7) out = yn @ W_out.T
    gemm_bf16<<<dim3(ROWS / 64, 192 / 64), 256, 0, stream>>>(
        yn_bf, w_out_bf, nullptr, (float*)d_out, nullptr, ROWS, DM, DI, 1);
}